// Round 12
// baseline (150.979 us; speedup 1.0000x reference)
//
#include <hip/hip_runtime.h>
#include <hip/hip_bf16.h>
#include <math.h>

#define N_RAYS   32768
#define N_SAMP   1048576
#define HID      64
#define ITERS    2                  // outer iters; each handles TWO 64-sample groups
#define BLK_HALF 1024               // per net: 1024 blk * 4 waves * 2 iters * 128 = 1,048,576
#define BLK_A    (2*BLK_HALF)       // blocks [0,1024): density, [1024,2048): rgb

typedef short bf8 __attribute__((ext_vector_type(8)));   // 8 x bf16 bits
typedef float f4  __attribute__((ext_vector_type(4)));

union BF8U { bf8 v; unsigned u[4]; };

// f32->bf16 pair pack via the C++ cast: the compiler fuses cast pairs into
// v_cvt_pk_bf16_f32 on gfx950. DO NOT replace with manual bit-twiddled RNE —
// R6 measured it 45% SLOWER (defeats the fusion; VALU-busy cyc 79k->101k).
static __device__ __forceinline__ unsigned bfbits(float x) {
    union { __bf16 h; unsigned short s; } c; c.h = (__bf16)x; return (unsigned)c.s;
}
static __device__ __forceinline__ unsigned pk2(float a, float b) {
#if __has_builtin(__builtin_amdgcn_cvt_pk_bf16_f32)
    return __builtin_bit_cast(unsigned, __builtin_amdgcn_cvt_pk_bf16_f32(a, b));
#else
    return bfbits(a) | (bfbits(b) << 16);
#endif
}
static __device__ __forceinline__ unsigned pk2r(float a, float b) {
    return pk2(fmaxf(a, 0.f), fmaxf(b, 0.f));
}
static __device__ __forceinline__ f4 mfma16(bf8 a, bf8 b, f4 c) {
    return __builtin_amdgcn_mfma_f32_16x16x32_bf16(a, b, c, 0, 0, 0);
}

// Fragment buffer layout (per net): 14 uint4 slots x 64 lanes (a1[0..3],
// a2[t*2+s -> 4..11], a3[12..13]) then 5 float4 slots x 64 lanes (bias2[0..3],
// bias3[4]). Every wave of that net loads the identical pattern -> L1-hot.
#define FRAG_SLOTS 14
#define BIAS_SLOTS 5

// ---------------------------------------------------------------------------
// Prep: ONE thread per (net,lane) builds all 19 fragment/bias slots.
// ---------------------------------------------------------------------------
__global__ __launch_bounds__(128) void prep_frags(
    const float* __restrict__ Wd1, const float* __restrict__ bd1,
    const float* __restrict__ Wd2, const float* __restrict__ bd2,
    const float* __restrict__ Wd3, const float* __restrict__ bd3,
    const float* __restrict__ Wr1, const float* __restrict__ br1,
    const float* __restrict__ Wr2, const float* __restrict__ br2,
    const float* __restrict__ Wr3, const float* __restrict__ br3,
    uint4* __restrict__ fragbuf, float4* __restrict__ biasbuf)
{
    const int tid  = threadIdx.x;
    if (tid >= 128) return;
    const int net  = tid >> 6;         // 0 = density, 1 = rgb
    const int lane = tid & 63;
    const int q    = lane >> 4;
    const int n    = lane & 15;
    const int qn   = n >> 2, rn = n & 3;
    const int rt   = n & 3;

    const float* W1 = net ? Wr1 : Wd1;  const float* b1 = net ? br1 : bd1;
    const float* W2 = net ? Wr2 : Wd2;  const float* b2 = net ? br2 : bd2;
    const float* W3 = net ? Wr3 : Wd3;  const float* b3 = net ? br3 : bd3;
    const int    nc = net ? 3 : 1;
    const int    ch = net ? (rt < 3 ? rt : 2) : 0;

    uint4*  fb = fragbuf + net * (FRAG_SLOTS * 64);
    float4* bb = biasbuf + net * (BIAS_SLOTS * 64);

    // A1 slots 0..3
    for (int t = 0; t < 4; ++t) {
        const int row = 8*qn + 4*(t&1) + rn + 32*(t>>1);
        uint4 f;
        f.x = pk2(W1[row],       W1[HID+row]);
        f.y = pk2(W1[2*HID+row], b1[row]);
        f.z = 0u; f.w = 0u;
        fb[t*64 + lane] = f;
    }
    // A2 slots 4..11  (slot = 4 + 2t + s)
    for (int t = 0; t < 4; ++t) {
        const int row = 8*qn + 4*(t&1) + rn + 32*(t>>1);
        for (int s = 0; s < 2; ++s) {
            unsigned u[4];
            for (int dw = 0; dw < 4; ++dw) {
                const int k = 8*q + 2*dw + 32*s;
                u[dw] = pk2(W2[k*HID+row], W2[(k+1)*HID+row]);
            }
            fb[(4 + 2*t + s)*64 + lane] = make_uint4(u[0], u[1], u[2], u[3]);
        }
    }
    // A3 slots 12..13
    for (int s = 0; s < 2; ++s) {
        unsigned u[4];
        for (int dw = 0; dw < 4; ++dw) {
            const int kg = 32*s + 8*q + 2*dw;
            u[dw] = pk2(W3[kg*nc + ch], W3[(kg+1)*nc + ch]);
        }
        fb[(12 + s)*64 + lane] = make_uint4(u[0], u[1], u[2], u[3]);
    }
    // bias2 slots 0..3
    for (int t = 0; t < 4; ++t) {
        float4 f;
        f.x = b2[8*q + 4*(t&1) + 0 + 32*(t>>1)];
        f.y = b2[8*q + 4*(t&1) + 1 + 32*(t>>1)];
        f.z = b2[8*q + 4*(t&1) + 2 + 32*(t>>1)];
        f.w = b2[8*q + 4*(t&1) + 3 + 32*(t>>1)];
        bb[t*64 + lane] = f;
    }
    // bias3 slot 4
    {
        float4 f;
        f.x = b3[0];
        f.y = net ? b3[1] : b3[0];
        f.z = net ? b3[2] : b3[0];
        f.w = net ? b3[2] : b3[0];
        bb[4*64 + lane] = f;
    }
}

// ---------------------------------------------------------------------------
// Pass A: SPLIT BY NET (R7) + PRE-PACKED FRAGMENTS (R10) + 2-WAY ILP (R12).
// R11 post-mortem: latency-bound — per-SIMD MFMA issue floor ~35k cyc vs
// ~119k wall; each u-tile chain (L1->pack->L2->pack->L3, ~300 cyc serial)
// runs with only ~3 resident waves. R12: each wave runs TWO independent
// 64-sample groups with their chains interleaved in the u-loop — in-wave ILP
// doubles MFMA-pipe fill without scheduler arbitration. (256,2) caps unified
// regs at 256 (est. ~220, no spill; tripwire = FETCH_SIZE ~7 MB).
// ---------------------------------------------------------------------------
__global__ __launch_bounds__(256, 2) void pass_a(
    const float* __restrict__ rays_o, const float* __restrict__ rays_d,
    const float* __restrict__ t_starts, const float* __restrict__ t_ends,
    const int*   __restrict__ ray_idx,
    const uint4* __restrict__ fragbuf, const float4* __restrict__ biasbuf,
    float* __restrict__ ws_sd, float* __restrict__ ws_r,
    float* __restrict__ ws_g,  float* __restrict__ ws_b,
    int* __restrict__ start)
{
    const bool is_rgb = blockIdx.x >= BLK_HALF;
    const int  blk    = is_rgb ? (blockIdx.x - BLK_HALF) : blockIdx.x;
    const int  lane   = threadIdx.x & 63;
    const int  wv     = ((blk << 8) + threadIdx.x) >> 6;   // 0..4095 per net
    const int  q      = lane >> 4;

    const uint4*  fb = fragbuf + (is_rgb ? FRAG_SLOTS*64 : 0);
    const float4* bb = biasbuf + (is_rgb ? BIAS_SLOTS*64 : 0);

    bf8 a1[4];
    #pragma unroll
    for (int t = 0; t < 4; ++t)
        a1[t] = __builtin_bit_cast(bf8, fb[t*64 + lane]);
    bf8 a2[4][2];
    #pragma unroll
    for (int t = 0; t < 4; ++t)
        #pragma unroll
        for (int s = 0; s < 2; ++s)
            a2[t][s] = __builtin_bit_cast(bf8, fb[(4 + 2*t + s)*64 + lane]);
    bf8 a3[2];
    #pragma unroll
    for (int s = 0; s < 2; ++s)
        a3[s] = __builtin_bit_cast(bf8, fb[(12 + s)*64 + lane]);
    f4 bias2[4];
    #pragma unroll
    for (int t = 0; t < 4; ++t)
        bias2[t] = __builtin_bit_cast(f4, bb[t*64 + lane]);
    f4 bias3 = __builtin_bit_cast(f4, bb[4*64 + lane]);

    const int base0 = wv * (ITERS * 128);

    #pragma unroll 1
    for (int it = 0; it < ITERS; ++it) {
        const int smpA = base0 + it * 128 + lane;
        const int smpB = smpA + 64;

        // ---- loads for both groups (independent, all in flight) ----
        const float tsA = t_starts[smpA], teA = t_ends[smpA];
        const float tsB = t_starts[smpB], teB = t_ends[smpB];
        const int   riA = ray_idx[smpA],  riB = ray_idx[smpB];
        const float midA = 0.5f*(tsA+teA), dtA = teA - tsA;
        const float midB = 0.5f*(tsB+teB), dtB = teB - tsB;
        const float pxA = rays_o[3*riA+0] + rays_d[3*riA+0]*midA;
        const float pyA = rays_o[3*riA+1] + rays_d[3*riA+1]*midA;
        const float pzA = rays_o[3*riA+2] + rays_d[3*riA+2]*midA;
        const float pxB = rays_o[3*riB+0] + rays_d[3*riB+0]*midB;
        const float pyB = rays_o[3*riB+1] + rays_d[3*riB+1]*midB;
        const float pzB = rays_o[3*riB+2] + rays_d[3*riB+2]*midB;
        const unsigned p01A = pk2(pxA, pyA), p23A = pk2(pzA, 1.0f);
        const unsigned p01B = pk2(pxB, pyB), p23B = pk2(pzB, 1.0f);

        if (!is_rgb) {
            // segment boundaries for both groups (density half only)
            int rpA = __shfl_up(riA, 1, 64);
            if (lane == 0) rpA = (smpA == 0) ? -1 : ray_idx[smpA-1];
            for (int rr = rpA + 1; rr <= riA; ++rr) start[rr] = smpA;
            int rpB = __shfl_up(riB, 1, 64);
            if (lane == 0) rpB = ray_idx[smpB-1];
            for (int rr = rpB + 1; rr <= riB; ++rr) start[rr] = smpB;
            if (smpB == N_SAMP - 1)
                for (int rr = riB + 1; rr <= N_RAYS; ++rr) start[rr] = N_SAMP;
        }

        f4 mineA = {0.f, 0.f, 0.f, 0.f};
        f4 mineB = {0.f, 0.f, 0.f, 0.f};

        #pragma unroll
        for (int u = 0; u < 4; ++u) {
            BF8U xbA, xbB;
            xbA.u[0] = (q == u) ? p01A : 0u;
            xbA.u[1] = (q == u) ? p23A : 0u;
            xbA.u[2] = 0u; xbA.u[3] = 0u;
            xbB.u[0] = (q == u) ? p01B : 0u;
            xbB.u[1] = (q == u) ? p23B : 0u;
            xbB.u[2] = 0u; xbB.u[3] = 0u;

            const f4 zero = {0.f, 0.f, 0.f, 0.f};
            f4 d1A[4], d1B[4];
            #pragma unroll
            for (int t = 0; t < 4; ++t) {
                d1A[t] = mfma16(a1[t], xbA.v, zero);
                d1B[t] = mfma16(a1[t], xbB.v, zero);
            }

            bf8 bf2A[2], bf2B[2];
            #pragma unroll
            for (int s = 0; s < 2; ++s) {
                BF8U pA, pB;
                pA.u[0] = pk2r(d1A[2*s][0],   d1A[2*s][1]);
                pA.u[1] = pk2r(d1A[2*s][2],   d1A[2*s][3]);
                pA.u[2] = pk2r(d1A[2*s+1][0], d1A[2*s+1][1]);
                pA.u[3] = pk2r(d1A[2*s+1][2], d1A[2*s+1][3]);
                pB.u[0] = pk2r(d1B[2*s][0],   d1B[2*s][1]);
                pB.u[1] = pk2r(d1B[2*s][2],   d1B[2*s][3]);
                pB.u[2] = pk2r(d1B[2*s+1][0], d1B[2*s+1][1]);
                pB.u[3] = pk2r(d1B[2*s+1][2], d1B[2*s+1][3]);
                bf2A[s] = pA.v; bf2B[s] = pB.v;
            }

            f4 d2A[4], d2B[4];
            #pragma unroll
            for (int t = 0; t < 4; ++t) {
                f4 aA = bias2[t];
                f4 aB = bias2[t];
                aA = mfma16(a2[t][0], bf2A[0], aA);
                aB = mfma16(a2[t][0], bf2B[0], aB);
                aA = mfma16(a2[t][1], bf2A[1], aA);
                aB = mfma16(a2[t][1], bf2B[1], aB);
                d2A[t] = aA; d2B[t] = aB;
            }

            bf8 bf3A[2], bf3B[2];
            #pragma unroll
            for (int s = 0; s < 2; ++s) {
                BF8U pA, pB;
                pA.u[0] = pk2r(d2A[2*s][0],   d2A[2*s][1]);
                pA.u[1] = pk2r(d2A[2*s][2],   d2A[2*s][3]);
                pA.u[2] = pk2r(d2A[2*s+1][0], d2A[2*s+1][1]);
                pA.u[3] = pk2r(d2A[2*s+1][2], d2A[2*s+1][3]);
                pB.u[0] = pk2r(d2B[2*s][0],   d2B[2*s][1]);
                pB.u[1] = pk2r(d2B[2*s][2],   d2B[2*s][3]);
                pB.u[2] = pk2r(d2B[2*s+1][0], d2B[2*s+1][1]);
                pB.u[3] = pk2r(d2B[2*s+1][2], d2B[2*s+1][3]);
                bf3A[s] = pA.v; bf3B[s] = pB.v;
            }

            f4 c3A = bias3, c3B = bias3;
            c3A = mfma16(a3[0], bf3A[0], c3A);
            c3B = mfma16(a3[0], bf3B[0], c3B);
            c3A = mfma16(a3[1], bf3A[1], c3A);
            c3B = mfma16(a3[1], bf3B[1], c3B);

            if (q == u) { mineA = c3A; mineB = c3B; }
        }

        // full-width epilogues: every lane handles its OWN two samples
        if (!is_rgb) {
            const float sgA = mineA[0];
            const float spA = fmaxf(sgA, 0.f) + __logf(1.f + __expf(-fabsf(sgA)));
            ws_sd[smpA] = spA * dtA;
            const float sgB = mineB[0];
            const float spB = fmaxf(sgB, 0.f) + __logf(1.f + __expf(-fabsf(sgB)));
            ws_sd[smpB] = spB * dtB;
        } else {
            ws_r[smpA] = __builtin_amdgcn_rcpf(1.f + __expf(-mineA[0]));
            ws_g[smpA] = __builtin_amdgcn_rcpf(1.f + __expf(-mineA[1]));
            ws_b[smpA] = __builtin_amdgcn_rcpf(1.f + __expf(-mineA[2]));
            ws_r[smpB] = __builtin_amdgcn_rcpf(1.f + __expf(-mineB[0]));
            ws_g[smpB] = __builtin_amdgcn_rcpf(1.f + __expf(-mineB[1]));
            ws_b[smpB] = __builtin_amdgcn_rcpf(1.f + __expf(-mineB[2]));
        }
    }
}

// ---------------------------------------------------------------------------
// Pass B: TWO rays per wave (32 lanes each). Telescoping weights
// w = exp(-excl) - exp(-incl); per-chunk closed-form opacity (no reduce).
// start[] clamped: rocprof dispatch-replay can hand this kernel re-poisoned
// (0xAA) workspace -> unguarded loop ran 41ms under profiling (R4).
// ---------------------------------------------------------------------------
__global__ __launch_bounds__(256) void pass_b(
    const float* __restrict__ t_starts, const float* __restrict__ t_ends,
    const float* __restrict__ ws_sd, const float* __restrict__ ws_r,
    const float* __restrict__ ws_g,  const float* __restrict__ ws_b,
    const int* __restrict__ start, float* __restrict__ out)
{
    const int lane = threadIdx.x & 63;
    const int wv   = (blockIdx.x * blockDim.x + threadIdx.x) >> 6;
    const int half = lane >> 5;
    const int l32  = lane & 31;
    const int r    = 2*wv + half;
    if (r >= N_RAYS) return;

    int s0 = start[r], s1 = start[r+1];
    s0 = min(max(s0, 0), N_SAMP);
    s1 = min(max(s1, s0), N_SAMP);

    float cum = 0.f, opac = 0.f, dist = 0.f, c0 = 0.f, c1 = 0.f, c2 = 0.f;

    for (int base = s0; base < s1; base += 32) {
        int s = base + l32;
        bool ok = s < s1;
        float sd  = ok ? ws_sd[s] : 0.f;
        float vr  = ok ? ws_r[s]  : 0.f;
        float vg  = ok ? ws_g[s]  : 0.f;
        float vb  = ok ? ws_b[s]  : 0.f;
        float mid = ok ? 0.5f*(t_starts[s] + t_ends[s]) : 0.f;

        float x = sd;                       // inclusive scan over 32 lanes
        #pragma unroll
        for (int off = 1; off < 32; off <<= 1) {
            float y = __shfl_up(x, off, 32);
            if (l32 >= off) x += y;
        }
        float incl = cum + x;
        float excl = incl - sd;
        float w = __expf(-excl) - __expf(-incl);   // trans*alpha, telescoped
        dist += w*mid; c0 += w*vr; c1 += w*vg; c2 += w*vb;

        float tot = __shfl(x, 31, 32);
        opac += __expf(-cum) - __expf(-(cum + tot));  // uniform across lanes
        cum  += tot;
    }

    #pragma unroll
    for (int off = 16; off > 0; off >>= 1) {
        dist += __shfl_xor(dist, off, 32);
        c0   += __shfl_xor(c0,   off, 32);
        c1   += __shfl_xor(c1,   off, 32);
        c2   += __shfl_xor(c2,   off, 32);
    }

    if (l32 == 0) {
        float rest = 1.f - opac;
        out[r*3 + 0] = c0 + 0.5f * rest;
        out[r*3 + 1] = c1 + 0.5f * rest;
        out[r*3 + 2] = c2 + 0.5f * rest;
        out[3*N_RAYS + r] = dist + 5.f * rest;
        out[4*N_RAYS + r] = opac;
    }
}

extern "C" void kernel_launch(void* const* d_in, const int* in_sizes, int n_in,
                              void* d_out, int out_size, void* d_ws, size_t ws_size,
                              hipStream_t stream) {
    const float* rays_o   = (const float*)d_in[0];
    const float* rays_d   = (const float*)d_in[1];
    const float* t_starts = (const float*)d_in[2];
    const float* t_ends   = (const float*)d_in[3];
    const int*   ray_idx  = (const int*)  d_in[4];
    const float* Wd1 = (const float*)d_in[5];  const float* bd1 = (const float*)d_in[6];
    const float* Wd2 = (const float*)d_in[7];  const float* bd2 = (const float*)d_in[8];
    const float* Wd3 = (const float*)d_in[9];  const float* bd3 = (const float*)d_in[10];
    const float* Wr1 = (const float*)d_in[11]; const float* br1 = (const float*)d_in[12];
    const float* Wr2 = (const float*)d_in[13]; const float* br2 = (const float*)d_in[14];
    const float* Wr3 = (const float*)d_in[15]; const float* br3 = (const float*)d_in[16];

    float* ws_sd = (float*)d_ws;                       // SoA planes, 4 MB each
    float* ws_r  = ws_sd + N_SAMP;
    float* ws_g  = ws_r  + N_SAMP;
    float* ws_b  = ws_g  + N_SAMP;
    char*  p     = (char*)(ws_b + N_SAMP);
    int*    start   = (int*)p;                         // (N_RAYS+1)*4 B
    uint4*  fragbuf = (uint4*)(p + (((N_RAYS+1)*4 + 255) & ~255));
    float4* biasbuf = (float4*)(fragbuf + 2*FRAG_SLOTS*64);
    float*  out     = (float*)d_out;

    hipLaunchKernelGGL(prep_frags, dim3(1), dim3(128), 0, stream,
                       Wd1, bd1, Wd2, bd2, Wd3, bd3,
                       Wr1, br1, Wr2, br2, Wr3, br3, fragbuf, biasbuf);

    hipLaunchKernelGGL(pass_a, dim3(BLK_A), dim3(256), 0, stream,
                       rays_o, rays_d, t_starts, t_ends, ray_idx,
                       fragbuf, biasbuf, ws_sd, ws_r, ws_g, ws_b, start);

    hipLaunchKernelGGL(pass_b, dim3((N_RAYS/2 * 64) / 256), dim3(256), 0, stream,
                       t_starts, t_ends, ws_sd, ws_r, ws_g, ws_b, start, out);
}

// Round 13
// 145.667 us; speedup vs baseline: 1.0365x; 1.0365x over previous
//
#include <hip/hip_runtime.h>
#include <hip/hip_bf16.h>
#include <math.h>

#define N_RAYS   32768
#define N_SAMP   1048576
#define HID      64
#define ITERS    4
#define BLK_HALF 1024               // per net: 1024 blk * 4 waves * 4 iters * 64 = 1,048,576
#define BLK_A    (2*BLK_HALF)       // blocks [0,1024): density, [1024,2048): rgb

typedef short bf8 __attribute__((ext_vector_type(8)));   // 8 x bf16 bits
typedef float f4  __attribute__((ext_vector_type(4)));

union BF8U { bf8 v; unsigned u[4]; };

// f32->bf16 pair pack via the C++ cast: the compiler fuses cast pairs into
// v_cvt_pk_bf16_f32 on gfx950. DO NOT replace with manual bit-twiddled RNE —
// R6 measured it 45% SLOWER (defeats the fusion; VALU-busy cyc 79k->101k).
static __device__ __forceinline__ unsigned bfbits(float x) {
    union { __bf16 h; unsigned short s; } c; c.h = (__bf16)x; return (unsigned)c.s;
}
static __device__ __forceinline__ unsigned pk2(float a, float b) {
#if __has_builtin(__builtin_amdgcn_cvt_pk_bf16_f32)
    return __builtin_bit_cast(unsigned, __builtin_amdgcn_cvt_pk_bf16_f32(a, b));
#else
    return bfbits(a) | (bfbits(b) << 16);
#endif
}
static __device__ __forceinline__ unsigned pk2r(float a, float b) {
    return pk2(fmaxf(a, 0.f), fmaxf(b, 0.f));
}
static __device__ __forceinline__ f4 mfma16(bf8 a, bf8 b, f4 c) {
    return __builtin_amdgcn_mfma_f32_16x16x32_bf16(a, b, c, 0, 0, 0);
}

// Fragment buffer layout (per net): 14 uint4 slots x 64 lanes (a1[0..3],
// a2[t*2+s -> 4..11], a3[12..13]) then 5 float4 slots x 64 lanes (bias2[0..3],
// bias3[4]). Every wave of that net loads the identical pattern -> L1-hot.
#define FRAG_SLOTS 14
#define BIAS_SLOTS 5

// ---------------------------------------------------------------------------
// Prep: ONE thread per (net,lane) builds all 19 fragment/bias slots.
// ---------------------------------------------------------------------------
__global__ __launch_bounds__(128) void prep_frags(
    const float* __restrict__ Wd1, const float* __restrict__ bd1,
    const float* __restrict__ Wd2, const float* __restrict__ bd2,
    const float* __restrict__ Wd3, const float* __restrict__ bd3,
    const float* __restrict__ Wr1, const float* __restrict__ br1,
    const float* __restrict__ Wr2, const float* __restrict__ br2,
    const float* __restrict__ Wr3, const float* __restrict__ br3,
    uint4* __restrict__ fragbuf, float4* __restrict__ biasbuf)
{
    const int tid  = threadIdx.x;
    if (tid >= 128) return;
    const int net  = tid >> 6;         // 0 = density, 1 = rgb
    const int lane = tid & 63;
    const int q    = lane >> 4;
    const int n    = lane & 15;
    const int qn   = n >> 2, rn = n & 3;
    const int rt   = n & 3;

    const float* W1 = net ? Wr1 : Wd1;  const float* b1 = net ? br1 : bd1;
    const float* W2 = net ? Wr2 : Wd2;  const float* b2 = net ? br2 : bd2;
    const float* W3 = net ? Wr3 : Wd3;  const float* b3 = net ? br3 : bd3;
    const int    nc = net ? 3 : 1;
    const int    ch = net ? (rt < 3 ? rt : 2) : 0;

    uint4*  fb = fragbuf + net * (FRAG_SLOTS * 64);
    float4* bb = biasbuf + net * (BIAS_SLOTS * 64);

    // A1 slots 0..3
    for (int t = 0; t < 4; ++t) {
        const int row = 8*qn + 4*(t&1) + rn + 32*(t>>1);
        uint4 f;
        f.x = pk2(W1[row],       W1[HID+row]);
        f.y = pk2(W1[2*HID+row], b1[row]);
        f.z = 0u; f.w = 0u;
        fb[t*64 + lane] = f;
    }
    // A2 slots 4..11  (slot = 4 + 2t + s)
    for (int t = 0; t < 4; ++t) {
        const int row = 8*qn + 4*(t&1) + rn + 32*(t>>1);
        for (int s = 0; s < 2; ++s) {
            unsigned u[4];
            for (int dw = 0; dw < 4; ++dw) {
                const int k = 8*q + 2*dw + 32*s;
                u[dw] = pk2(W2[k*HID+row], W2[(k+1)*HID+row]);
            }
            fb[(4 + 2*t + s)*64 + lane] = make_uint4(u[0], u[1], u[2], u[3]);
        }
    }
    // A3 slots 12..13
    for (int s = 0; s < 2; ++s) {
        unsigned u[4];
        for (int dw = 0; dw < 4; ++dw) {
            const int kg = 32*s + 8*q + 2*dw;
            u[dw] = pk2(W3[kg*nc + ch], W3[(kg+1)*nc + ch]);
        }
        fb[(12 + s)*64 + lane] = make_uint4(u[0], u[1], u[2], u[3]);
    }
    // bias2 slots 0..3
    for (int t = 0; t < 4; ++t) {
        float4 f;
        f.x = b2[8*q + 4*(t&1) + 0 + 32*(t>>1)];
        f.y = b2[8*q + 4*(t&1) + 1 + 32*(t>>1)];
        f.z = b2[8*q + 4*(t&1) + 2 + 32*(t>>1)];
        f.w = b2[8*q + 4*(t&1) + 3 + 32*(t>>1)];
        bb[t*64 + lane] = f;
    }
    // bias3 slot 4
    {
        float4 f;
        f.x = b3[0];
        f.y = net ? b3[1] : b3[0];
        f.z = net ? b3[2] : b3[0];
        f.w = net ? b3[2] : b3[0];
        bb[4*64 + lane] = f;
    }
}

// ---------------------------------------------------------------------------
// Pass A: SPLIT BY NET (R7) + PRE-PACKED FRAGMENTS (R10) + (256,3) (R11).
// R12 post-mortem: 2-way in-wave ILP was sequentialized by the register
// allocator (VGPR_Count unchanged, occupancy fell) — reverted to R11 (best).
// True unified VGPR+AGPR footprint ~160/wave caps residency at 3 waves/SIMD;
// pass_a is wave-serial-latency bound at ~50 us (MFMA issue floor ~15 us).
// R13 delta: AoS output — ws4[s] = {r,g,b,sd} (byte-disjoint partial stores
// from the two halves; L2 has per-byte write masks) + mid plane, so pass_b's
// per-sample load chain drops 6 -> 2 loads.
// Spill tripwire: FETCH_SIZE must stay ~7 MB (R4: spill -> 852 MB).
// ---------------------------------------------------------------------------
__global__ __launch_bounds__(256, 3) void pass_a(
    const float* __restrict__ rays_o, const float* __restrict__ rays_d,
    const float* __restrict__ t_starts, const float* __restrict__ t_ends,
    const int*   __restrict__ ray_idx,
    const uint4* __restrict__ fragbuf, const float4* __restrict__ biasbuf,
    float4* __restrict__ ws4, float* __restrict__ ws_mid,
    int* __restrict__ start)
{
    const bool is_rgb = blockIdx.x >= BLK_HALF;
    const int  blk    = is_rgb ? (blockIdx.x - BLK_HALF) : blockIdx.x;
    const int  lane   = threadIdx.x & 63;
    const int  wv     = ((blk << 8) + threadIdx.x) >> 6;   // 0..4095 per net
    const int  q      = lane >> 4;

    const uint4*  fb = fragbuf + (is_rgb ? FRAG_SLOTS*64 : 0);
    const float4* bb = biasbuf + (is_rgb ? BIAS_SLOTS*64 : 0);

    bf8 a1[4];
    #pragma unroll
    for (int t = 0; t < 4; ++t)
        a1[t] = __builtin_bit_cast(bf8, fb[t*64 + lane]);
    bf8 a2[4][2];
    #pragma unroll
    for (int t = 0; t < 4; ++t)
        #pragma unroll
        for (int s = 0; s < 2; ++s)
            a2[t][s] = __builtin_bit_cast(bf8, fb[(4 + 2*t + s)*64 + lane]);
    bf8 a3[2];
    #pragma unroll
    for (int s = 0; s < 2; ++s)
        a3[s] = __builtin_bit_cast(bf8, fb[(12 + s)*64 + lane]);
    f4 bias2[4];
    #pragma unroll
    for (int t = 0; t < 4; ++t)
        bias2[t] = __builtin_bit_cast(f4, bb[t*64 + lane]);
    f4 bias3 = __builtin_bit_cast(f4, bb[4*64 + lane]);

    const int base0 = wv * (ITERS * 64);

    #pragma unroll 1
    for (int it = 0; it < ITERS; ++it) {
        const int smp = base0 + it * 64 + lane;

        const float ts = t_starts[smp], te = t_ends[smp];
        const int   ri = ray_idx[smp];
        const float mid = 0.5f*(ts+te), dt = te - ts;
        const float px = rays_o[3*ri+0] + rays_d[3*ri+0]*mid;
        const float py = rays_o[3*ri+1] + rays_d[3*ri+1]*mid;
        const float pz = rays_o[3*ri+2] + rays_d[3*ri+2]*mid;
        const unsigned p01 = pk2(px, py);
        const unsigned p23 = pk2(pz, 1.0f);

        if (!is_rgb) {
            // segment boundaries (density half only)
            int rp = __shfl_up(ri, 1, 64);
            if (lane == 0) rp = (smp == 0) ? -1 : ray_idx[smp-1];
            for (int rr = rp + 1; rr <= ri; ++rr) start[rr] = smp;
            if (smp == N_SAMP - 1)
                for (int rr = ri + 1; rr <= N_RAYS; ++rr) start[rr] = N_SAMP;
        }

        f4 mine = {0.f, 0.f, 0.f, 0.f};

        #pragma unroll
        for (int u = 0; u < 4; ++u) {
            BF8U xb;
            xb.u[0] = (q == u) ? p01 : 0u;
            xb.u[1] = (q == u) ? p23 : 0u;
            xb.u[2] = 0u; xb.u[3] = 0u;

            const f4 zero = {0.f, 0.f, 0.f, 0.f};
            f4 d1[4];
            #pragma unroll
            for (int t = 0; t < 4; ++t) d1[t] = mfma16(a1[t], xb.v, zero);

            bf8 bf2[2];
            #pragma unroll
            for (int s = 0; s < 2; ++s) {
                BF8U p;
                p.u[0] = pk2r(d1[2*s][0],   d1[2*s][1]);
                p.u[1] = pk2r(d1[2*s][2],   d1[2*s][3]);
                p.u[2] = pk2r(d1[2*s+1][0], d1[2*s+1][1]);
                p.u[3] = pk2r(d1[2*s+1][2], d1[2*s+1][3]);
                bf2[s] = p.v;
            }

            f4 d2[4];
            #pragma unroll
            for (int t = 0; t < 4; ++t) {
                f4 a = bias2[t];
                a = mfma16(a2[t][0], bf2[0], a);
                a = mfma16(a2[t][1], bf2[1], a);
                d2[t] = a;
            }

            bf8 bf3[2];
            #pragma unroll
            for (int s = 0; s < 2; ++s) {
                BF8U p;
                p.u[0] = pk2r(d2[2*s][0],   d2[2*s][1]);
                p.u[1] = pk2r(d2[2*s][2],   d2[2*s][3]);
                p.u[2] = pk2r(d2[2*s+1][0], d2[2*s+1][1]);
                p.u[3] = pk2r(d2[2*s+1][2], d2[2*s+1][3]);
                bf3[s] = p.v;
            }

            f4 c3 = bias3;
            c3 = mfma16(a3[0], bf3[0], c3);
            c3 = mfma16(a3[1], bf3[1], c3);

            if (q == u) mine = c3;   // lane's own sample's outputs
        }

        // full-width epilogue: byte-disjoint partial stores into ws4[smp]
        float* w4 = (float*)(ws4 + smp);
        if (!is_rgb) {
            const float sg = mine[0];
            const float sp = fmaxf(sg, 0.f) + __logf(1.f + __expf(-fabsf(sg)));
            w4[3] = sp * dt;            // .w = sigma_dt
            ws_mid[smp] = mid;          // mid plane (saves pass_b two loads)
        } else {
            w4[0] = __builtin_amdgcn_rcpf(1.f + __expf(-mine[0]));
            w4[1] = __builtin_amdgcn_rcpf(1.f + __expf(-mine[1]));
            w4[2] = __builtin_amdgcn_rcpf(1.f + __expf(-mine[2]));
        }
    }
}

// ---------------------------------------------------------------------------
// Pass B: TWO rays per wave (32 lanes each). Telescoping weights
// w = exp(-excl) - exp(-incl); per-chunk closed-form opacity (no reduce).
// R13: 2 loads per sample (float4 + mid) instead of 6 — shorter VMEM chain.
// start[] clamped: rocprof dispatch-replay can hand this kernel re-poisoned
// (0xAA) workspace -> unguarded loop ran 41ms under profiling (R4).
// ---------------------------------------------------------------------------
__global__ __launch_bounds__(256) void pass_b(
    const float4* __restrict__ ws4, const float* __restrict__ ws_mid,
    const int* __restrict__ start, float* __restrict__ out)
{
    const int lane = threadIdx.x & 63;
    const int wv   = (blockIdx.x * blockDim.x + threadIdx.x) >> 6;
    const int half = lane >> 5;
    const int l32  = lane & 31;
    const int r    = 2*wv + half;
    if (r >= N_RAYS) return;

    int s0 = start[r], s1 = start[r+1];
    s0 = min(max(s0, 0), N_SAMP);
    s1 = min(max(s1, s0), N_SAMP);

    float cum = 0.f, opac = 0.f, dist = 0.f, c0 = 0.f, c1 = 0.f, c2 = 0.f;

    for (int base = s0; base < s1; base += 32) {
        int s = base + l32;
        bool ok = s < s1;
        float4 v  = ok ? ws4[s]    : make_float4(0.f, 0.f, 0.f, 0.f);
        float mid = ok ? ws_mid[s] : 0.f;
        float sd  = v.w;

        float x = sd;                       // inclusive scan over 32 lanes
        #pragma unroll
        for (int off = 1; off < 32; off <<= 1) {
            float y = __shfl_up(x, off, 32);
            if (l32 >= off) x += y;
        }
        float incl = cum + x;
        float excl = incl - sd;
        float w = __expf(-excl) - __expf(-incl);   // trans*alpha, telescoped
        dist += w*mid; c0 += w*v.x; c1 += w*v.y; c2 += w*v.z;

        float tot = __shfl(x, 31, 32);
        opac += __expf(-cum) - __expf(-(cum + tot));  // uniform across lanes
        cum  += tot;
    }

    #pragma unroll
    for (int off = 16; off > 0; off >>= 1) {
        dist += __shfl_xor(dist, off, 32);
        c0   += __shfl_xor(c0,   off, 32);
        c1   += __shfl_xor(c1,   off, 32);
        c2   += __shfl_xor(c2,   off, 32);
    }

    if (l32 == 0) {
        float rest = 1.f - opac;
        out[r*3 + 0] = c0 + 0.5f * rest;
        out[r*3 + 1] = c1 + 0.5f * rest;
        out[r*3 + 2] = c2 + 0.5f * rest;
        out[3*N_RAYS + r] = dist + 5.f * rest;
        out[4*N_RAYS + r] = opac;
    }
}

extern "C" void kernel_launch(void* const* d_in, const int* in_sizes, int n_in,
                              void* d_out, int out_size, void* d_ws, size_t ws_size,
                              hipStream_t stream) {
    const float* rays_o   = (const float*)d_in[0];
    const float* rays_d   = (const float*)d_in[1];
    const float* t_starts = (const float*)d_in[2];
    const float* t_ends   = (const float*)d_in[3];
    const int*   ray_idx  = (const int*)  d_in[4];
    const float* Wd1 = (const float*)d_in[5];  const float* bd1 = (const float*)d_in[6];
    const float* Wd2 = (const float*)d_in[7];  const float* bd2 = (const float*)d_in[8];
    const float* Wd3 = (const float*)d_in[9];  const float* bd3 = (const float*)d_in[10];
    const float* Wr1 = (const float*)d_in[11]; const float* br1 = (const float*)d_in[12];
    const float* Wr2 = (const float*)d_in[13]; const float* br2 = (const float*)d_in[14];
    const float* Wr3 = (const float*)d_in[15]; const float* br3 = (const float*)d_in[16];

    float4* ws4    = (float4*)d_ws;                    // 16 MB AoS {r,g,b,sd}
    float*  ws_mid = (float*)(ws4 + N_SAMP);           // 4 MB mid plane
    char*   p      = (char*)(ws_mid + N_SAMP);
    int*    startb  = (int*)p;                         // (N_RAYS+1)*4 B
    uint4*  fragbuf = (uint4*)(p + (((N_RAYS+1)*4 + 255) & ~255));
    float4* biasbuf = (float4*)(fragbuf + 2*FRAG_SLOTS*64);
    float*  out     = (float*)d_out;

    hipLaunchKernelGGL(prep_frags, dim3(1), dim3(128), 0, stream,
                       Wd1, bd1, Wd2, bd2, Wd3, bd3,
                       Wr1, br1, Wr2, br2, Wr3, br3, fragbuf, biasbuf);

    hipLaunchKernelGGL(pass_a, dim3(BLK_A), dim3(256), 0, stream,
                       rays_o, rays_d, t_starts, t_ends, ray_idx,
                       fragbuf, biasbuf, ws4, ws_mid, startb);

    hipLaunchKernelGGL(pass_b, dim3((N_RAYS/2 * 64) / 256), dim3(256), 0, stream,
                       ws4, ws_mid, startb, out);
}